// Round 11
// baseline (18630.414 us; speedup 1.0000x reference)
//
#include <hip/hip_runtime.h>

#define TSTEPS 784
#define BATCH  256
#define HDIM   512
#define NCLS   10
#define NGRP   16   // 16 groups x 16 batch rows; one WG (one CU) per group

typedef __bf16 bf16x8 __attribute__((ext_vector_type(8)));
typedef float  f32x4  __attribute__((ext_vector_type(4)));
typedef unsigned uint4v __attribute__((ext_vector_type(4)));
typedef unsigned short u16;

static __device__ __forceinline__ u16 f2bf(float f) {
  unsigned u = __builtin_bit_cast(unsigned, f);
  u += 0x7fffu + ((u >> 16) & 1u);
  return (u16)(u >> 16);
}
static __device__ __forceinline__ float bf2f(unsigned s) {
  unsigned u = s << 16;
  return __builtin_bit_cast(float, u);
}

// ---------------- xp[t][b] = inputs[b][perm[t]] ----------------
__global__ __launch_bounds__(256) void gather_xp(const float* __restrict__ in,
                                                 const int* __restrict__ perm,
                                                 float* __restrict__ xp) {
  int t = blockIdx.x;
  int b = threadIdx.x;
  int p = perm[t];
  p = (p < 0) ? 0 : (p >= TSTEPS ? TSTEPS - 1 : p);
  xp[t * BATCH + b] = in[b * TSTEPS + p];
}

// ---------------- X = (triu(W,1) - triu(W,1)^T) / 32 ----------------
__global__ __launch_bounds__(256) void build_X(const float* __restrict__ W,
                                               float* __restrict__ X) {
  int idx = blockIdx.x * 256 + threadIdx.x;
  int i = idx >> 9, j = idx & 511;
  float v = 0.f;
  if (j > i) v = W[i * HDIM + j];
  else if (i > j) v = -W[j * HDIM + i];
  X[idx] = v * 0.03125f;
}

// ---------------- P = coef*X + I ----------------
__global__ __launch_bounds__(256) void axpyI(float* __restrict__ P,
                                             const float* __restrict__ X, float coef) {
  int idx = blockIdx.x * 256 + threadIdx.x;
  int i = idx >> 9, j = idx & 511;
  P[idx] = coef * X[idx] + ((i == j) ? 1.f : 0.f);
}

// ---------------- C = alpha*A*B (+I), 512^3 fp32 [R2-R10 proven] ----------------
// expm chain needs fp32-class accuracy (R9: split-bf16 here -> absmax 12).
__global__ __launch_bounds__(256) void gemm512(float* __restrict__ C,
                                               const float* __restrict__ A,
                                               const float* __restrict__ B,
                                               float alpha, int addI) {
  __shared__ float As[16][68];
  __shared__ float Bs[16][68];
  const int tx = threadIdx.x, ty = threadIdx.y;
  const int tid = ty * 16 + tx;
  const int ib = blockIdx.y, jb = blockIdx.x;
  const int ra = tid >> 2, ca = (tid & 3) << 2;
  const int rb = tid >> 4, cb = (tid & 15) << 2;
  float acc[4][4] = {};
  for (int kt = 0; kt < HDIM / 16; ++kt) {
    f32x4 av = *(const f32x4*)(A + (ib * 64 + ra) * HDIM + kt * 16 + ca);
    f32x4 bv = *(const f32x4*)(B + (kt * 16 + rb) * HDIM + jb * 64 + cb);
    __syncthreads();
    As[ca + 0][ra] = av[0];
    As[ca + 1][ra] = av[1];
    As[ca + 2][ra] = av[2];
    As[ca + 3][ra] = av[3];
    *(f32x4*)&Bs[rb][cb] = bv;
    __syncthreads();
#pragma unroll
    for (int kk = 0; kk < 16; ++kk) {
      f32x4 a4 = *(const f32x4*)&As[kk][ty << 2];
      f32x4 b4 = *(const f32x4*)&Bs[kk][tx << 2];
#pragma unroll
      for (int u = 0; u < 4; ++u)
#pragma unroll
        for (int v = 0; v < 4; ++v) acc[u][v] = fmaf(a4[u], b4[v], acc[u][v]);
    }
  }
#pragma unroll
  for (int u = 0; u < 4; ++u)
#pragma unroll
    for (int v = 0; v < 4; ++v) {
      int r = ib * 64 + (ty << 2) + u, c = jb * 64 + (tx << 2) + v;
      float val = alpha * acc[u][v];
      if (addI && r == c) val += 1.f;
      C[r * HDIM + c] = val;
    }
}

// ---------------- persistent RNN scan: FULLY WG-LOCAL ----------------
// 16 WGs x 1024 thr (16 waves). Group gb = blockIdx.x owns batch rows
// [gb*16, gb*16+16). Wave w owns cols [w*32, w*32+32) (two 16-col MFMA tiles;
// B hi/lo = 256 regs/wave -> ~330 total, fits 512/wave cap at 4 waves/SIMD).
// h NEVER leaves the CU: ping-pong between two LDS buffers (hi/lo u16 planes,
// R10-proven layout: plane row = 256 dwords, phys = (row<<8)|(du^((row&7)<<2))).
// One __syncthreads per step replaces all flags/fences/MALL hops. Step t reads
// buf[t&1], writes buf[1-(t&1)]; reads(t) complete before sync(t), writes(t+1)
// start after it -> single barrier is sufficient. No atomics, no spin loops.
__global__ __launch_bounds__(1024, 1) void rnn_main(
    const float* __restrict__ xp, const float* __restrict__ Borth,
    const float* __restrict__ W_in, const float* __restrict__ b_mod,
    const float* __restrict__ W_lin, const float* __restrict__ b_lin,
    float* __restrict__ out) {
  __shared__ unsigned tHi[2][4096];  // 2 x 16 KB (16 rows x 256 dwords = 512 u16 cols)
  __shared__ unsigned tLo[2][4096];  // 2 x 16 KB

  const int gb = blockIdx.x;
  const int tid = threadIdx.x;
  const int w = tid >> 6;     // wave 0..15
  const int lane = tid & 63;
  const int quad = lane >> 4;
  const int l16 = lane & 15;
  const int col0 = (w << 5) + l16;  // ct=0 column
  const int col1 = col0 + 16;       // ct=1 column
  const unsigned swz = (unsigned)((l16 & 7) << 2);

  // ---- B fragments for both col-tiles (round-hi split, proven numerics) ----
  bf16x8 B0h[16], B0l[16], B1h[16], B1l[16];
#pragma unroll
  for (int ki = 0; ki < 16; ++ki) {
#pragma unroll
    for (int j = 0; j < 8; ++j) {
      int k = (ki << 5) + (quad << 3) + j;
      float v0 = Borth[k * HDIM + col0];
      float v1 = Borth[k * HDIM + col1];
      u16 h0 = f2bf(v0), h1 = f2bf(v1);
      B0h[ki][j] = __builtin_bit_cast(__bf16, h0);
      B0l[ki][j] = __builtin_bit_cast(__bf16, f2bf(v0 - bf2f(h0)));
      B1h[ki][j] = __builtin_bit_cast(__bf16, h1);
      B1l[ki][j] = __builtin_bit_cast(__bf16, f2bf(v1 - bf2f(h1)));
    }
  }
  const float win0 = W_in[col0], win1 = W_in[col1];
  const float bm0 = b_mod[col0], bm1 = b_mod[col1];

  // ---- h_0 = 0 in buffer 0 ----
#pragma unroll
  for (int i = 0; i < 4; ++i) {
    tHi[0][tid + (i << 10)] = 0u;
    tLo[0][tid + (i << 10)] = 0u;
  }
  __syncthreads();

  for (int t = 0; t < TSTEPS; ++t) {
    const unsigned* __restrict__ cH = tHi[t & 1];
    const unsigned* __restrict__ cL = tLo[t & 1];
    u16* __restrict__ nH = (u16*)tHi[1 - (t & 1)];
    u16* __restrict__ nL = (u16*)tLo[1 - (t & 1)];

    // ---- fragment reads (R10-proven swizzled path) + split-bf16 MFMA ----
    f32x4 a0hh = {0.f, 0.f, 0.f, 0.f}, a0lh = a0hh, a0hl = a0hh;
    f32x4 a1hh = a0hh, a1lh = a0hh, a1hl = a0hh;
#pragma unroll
    for (int ki = 0; ki < 16; ++ki) {
      unsigned dcol0 = (unsigned)((ki << 4) + (quad << 2));
      unsigned off = ((unsigned)l16 << 8) + (dcol0 ^ swz);
      bf16x8 ah = __builtin_bit_cast(bf16x8, *(const uint4v*)(cH + off));
      bf16x8 al = __builtin_bit_cast(bf16x8, *(const uint4v*)(cL + off));
      a0hh = __builtin_amdgcn_mfma_f32_16x16x32_bf16(ah, B0h[ki], a0hh, 0, 0, 0);
      a0lh = __builtin_amdgcn_mfma_f32_16x16x32_bf16(al, B0h[ki], a0lh, 0, 0, 0);
      a0hl = __builtin_amdgcn_mfma_f32_16x16x32_bf16(ah, B0l[ki], a0hl, 0, 0, 0);
      a1hh = __builtin_amdgcn_mfma_f32_16x16x32_bf16(ah, B1h[ki], a1hh, 0, 0, 0);
      a1lh = __builtin_amdgcn_mfma_f32_16x16x32_bf16(al, B1h[ki], a1lh, 0, 0, 0);
      a1hl = __builtin_amdgcn_mfma_f32_16x16x32_bf16(ah, B1l[ki], a1hl, 0, 0, 0);
    }

    // ---- epilogue: C/D row = quad*4+r, col = l16 [R3-proven]; write LDS ----
    const f32x4 xps = *(const f32x4*)(xp + t * BATCH + (gb << 4) + (quad << 2));
#pragma unroll
    for (int r = 0; r < 4; ++r) {
      int row = (quad << 2) + r;
      unsigned rsw = (unsigned)((row & 7) << 2);
      // ct = 0
      {
        float pre = a0hh[r] + a0lh[r] + a0hl[r] + xps[r] * win0;
        float mm = fmaxf(fabsf(pre) + bm0, 0.f);
        float hv = (pre > 0.f) ? mm : ((pre < 0.f) ? -mm : 0.f);
        u16 hbv = f2bf(hv);
        u16 lbv = f2bf(hv - bf2f(hbv));
        unsigned du = (unsigned)(col0 >> 1);
        unsigned phys = ((unsigned)row << 8) | (du ^ rsw);
        unsigned slot = phys * 2 + (unsigned)(col0 & 1);
        nH[slot] = hbv;
        nL[slot] = lbv;
      }
      // ct = 1
      {
        float pre = a1hh[r] + a1lh[r] + a1hl[r] + xps[r] * win1;
        float mm = fmaxf(fabsf(pre) + bm1, 0.f);
        float hv = (pre > 0.f) ? mm : ((pre < 0.f) ? -mm : 0.f);
        u16 hbv = f2bf(hv);
        u16 lbv = f2bf(hv - bf2f(hbv));
        unsigned du = (unsigned)(col1 >> 1);
        unsigned phys = ((unsigned)row << 8) | (du ^ rsw);
        unsigned slot = phys * 2 + (unsigned)(col1 & 1);
        nH[slot] = hbv;
        nL[slot] = lbv;
      }
    }
    __syncthreads();  // h_{t+1} complete; also fences reads(t) vs writes(t+1)
  }

  // ---- head: h_784 in buffer 0 (784 even) ----
  if (tid < 256) {
    int row = tid >> 4;
    int cls = tid & 15;
    if (cls < NCLS) {
      float s = b_lin[cls];
      const float* wl = W_lin + cls * HDIM;
      const u16* fH = (const u16*)tHi[0];
      const u16* fL = (const u16*)tLo[0];
      unsigned rsw = (unsigned)((row & 7) << 2);
      for (int k = 0; k < HDIM; ++k) {
        unsigned phys = ((unsigned)row << 8) | (((unsigned)(k >> 1)) ^ rsw);
        unsigned slot = phys * 2 + (unsigned)(k & 1);
        s = fmaf(bf2f(fH[slot]) + bf2f(fL[slot]), wl[k], s);
      }
      out[((gb << 4) + row) * NCLS + cls] = s;
    }
  }
}

extern "C" void kernel_launch(void* const* d_in, const int* in_sizes, int n_in,
                              void* d_out, int out_size, void* d_ws, size_t ws_size,
                              hipStream_t stream) {
  const float* inputs = (const float*)d_in[0];  // 256x784
  const int* perm = (const int*)d_in[1];        // 784 (int64 -> int32 by harness)
  const float* W_skew = (const float*)d_in[2];  // 512x512
  const float* W_in = (const float*)d_in[3];    // 512
  const float* b_mod = (const float*)d_in[4];   // 512
  const float* W_lin = (const float*)d_in[5];   // 10x512
  const float* b_lin = (const float*)d_in[6];   // 10
  float* out = (float*)d_out;

  char* ws = (char*)d_ws;
  float* xp = (float*)ws;            // 0.77 MB
  float* X = xp + TSTEPS * BATCH;    // 1 MB
  float* P = X + HDIM * HDIM;        // 1 MB
  float* Q = P + HDIM * HDIM;        // 1 MB  (total ~3.8 MB; no h buffers needed)

  gather_xp<<<TSTEPS, 256, 0, stream>>>(inputs, perm, xp);
  build_X<<<(HDIM * HDIM) / 256, 256, 0, stream>>>(W_skew, X);

  // expm(A) = (T6(A/32))^(2^5), Horner -- fp32 gemm512 [proven numerics]
  axpyI<<<(HDIM * HDIM) / 256, 256, 0, stream>>>(P, X, 1.f / 6.f);
  float* a = P;
  float* b = Q;
  for (int k = 5; k >= 1; --k) {
    gemm512<<<dim3(8, 8), dim3(16, 16), 0, stream>>>(b, X, a, 1.f / (float)k, 1);
    float* tmp = a; a = b; b = tmp;
  }
  for (int i = 0; i < 5; ++i) {
    gemm512<<<dim3(8, 8), dim3(16, 16), 0, stream>>>(b, a, a, 1.f, 0);
    float* tmp = a; a = b; b = tmp;
  }
  // a == P (10 swaps -> back to P)

  rnn_main<<<NGRP, 1024, 0, stream>>>(xp, a, W_in, b_mod, W_lin, b_lin, out);
  (void)in_sizes; (void)n_in; (void)out_size; (void)ws_size;
}

// Round 12
// 2915.205 us; speedup vs baseline: 6.3908x; 6.3908x over previous
//
#include <hip/hip_runtime.h>

#define TSTEPS 784
#define BATCH  256
#define HDIM   512
#define NCLS   10
#define NGRP   16
#define WGPG   8

typedef __bf16 bf16x8 __attribute__((ext_vector_type(8)));
typedef float  f32x4  __attribute__((ext_vector_type(4)));
typedef unsigned uint4v __attribute__((ext_vector_type(4)));
typedef unsigned long long u64;
typedef unsigned short u16;

static __device__ __forceinline__ u16 f2bf(float f) {
  unsigned u = __builtin_bit_cast(unsigned, f);
  u += 0x7fffu + ((u >> 16) & 1u);
  return (u16)(u >> 16);
}
static __device__ __forceinline__ float bf2f(unsigned s) {
  unsigned u = s << 16;
  return __builtin_bit_cast(float, u);
}

// ---------------- xp[t][b] = inputs[b][perm[t]] ----------------
__global__ __launch_bounds__(256) void gather_xp(const float* __restrict__ in,
                                                 const int* __restrict__ perm,
                                                 float* __restrict__ xp) {
  int t = blockIdx.x;
  int b = threadIdx.x;
  int p = perm[t];
  p = (p < 0) ? 0 : (p >= TSTEPS ? TSTEPS - 1 : p);
  xp[t * BATCH + b] = in[b * TSTEPS + p];
}

// ---------------- X = (triu(W,1) - triu(W,1)^T) / 32 ----------------
__global__ __launch_bounds__(256) void build_X(const float* __restrict__ W,
                                               float* __restrict__ X) {
  int idx = blockIdx.x * 256 + threadIdx.x;
  int i = idx >> 9, j = idx & 511;
  float v = 0.f;
  if (j > i) v = W[i * HDIM + j];
  else if (i > j) v = -W[j * HDIM + i];
  X[idx] = v * 0.03125f;
}

// ---------------- P = coef*X + I ----------------
__global__ __launch_bounds__(256) void axpyI(float* __restrict__ P,
                                             const float* __restrict__ X, float coef) {
  int idx = blockIdx.x * 256 + threadIdx.x;
  int i = idx >> 9, j = idx & 511;
  P[idx] = coef * X[idx] + ((i == j) ? 1.f : 0.f);
}

// ---------------- C = alpha*A*B (+I), 512^3 fp32 [R2-R10 proven] ----------------
// expm chain needs fp32-class accuracy (R9: split-bf16 here -> absmax 12).
__global__ __launch_bounds__(256) void gemm512(float* __restrict__ C,
                                               const float* __restrict__ A,
                                               const float* __restrict__ B,
                                               float alpha, int addI) {
  __shared__ float As[16][68];
  __shared__ float Bs[16][68];
  const int tx = threadIdx.x, ty = threadIdx.y;
  const int tid = ty * 16 + tx;
  const int ib = blockIdx.y, jb = blockIdx.x;
  const int ra = tid >> 2, ca = (tid & 3) << 2;
  const int rb = tid >> 4, cb = (tid & 15) << 2;
  float acc[4][4] = {};
  for (int kt = 0; kt < HDIM / 16; ++kt) {
    f32x4 av = *(const f32x4*)(A + (ib * 64 + ra) * HDIM + kt * 16 + ca);
    f32x4 bv = *(const f32x4*)(B + (kt * 16 + rb) * HDIM + jb * 64 + cb);
    __syncthreads();
    As[ca + 0][ra] = av[0];
    As[ca + 1][ra] = av[1];
    As[ca + 2][ra] = av[2];
    As[ca + 3][ra] = av[3];
    *(f32x4*)&Bs[rb][cb] = bv;
    __syncthreads();
#pragma unroll
    for (int kk = 0; kk < 16; ++kk) {
      f32x4 a4 = *(const f32x4*)&As[kk][ty << 2];
      f32x4 b4 = *(const f32x4*)&Bs[kk][tx << 2];
#pragma unroll
      for (int u = 0; u < 4; ++u)
#pragma unroll
        for (int v = 0; v < 4; ++v) acc[u][v] = fmaf(a4[u], b4[v], acc[u][v]);
    }
  }
#pragma unroll
  for (int u = 0; u < 4; ++u)
#pragma unroll
    for (int v = 0; v < 4; ++v) {
      int r = ib * 64 + (ty << 2) + u, c = jb * 64 + (tx << 2) + v;
      float val = alpha * acc[u][v];
      if (addI && r == c) val += 1.f;
      C[r * HDIM + c] = val;
    }
}

// ---------------- persistent RNN scan: R10 + per-wave flags ----------------
// 128 WGs x 256 thr (4 waves). gb = wg&15, cg = wg>>4. h in global as hi/lo
// u16 planes [R10-proven]. PER-WAVE flags (32/group): each wave drains its own
// stores (vmcnt is per-wave) and flags immediately -- no WG barrier before
// flagging. Poll-success (all 32 waves flagged t+1) implies every wave's
// ds_reads of tile(t) are done, so the tile-reuse __syncthreads is SUBSUMED:
// exactly ONE __syncthreads per step (stage-write -> ds_read ordering).
// B per wave = 128 regs (AGPR-resident, under the 256 cap -- R11's lesson).
__global__ __launch_bounds__(256, 1) void rnn_main(
    const float* __restrict__ xp, const float* __restrict__ Borth,
    const float* __restrict__ W_in, const float* __restrict__ b_mod,
    const float* __restrict__ W_lin, const float* __restrict__ b_lin,
    u16* __restrict__ h0hi, u16* __restrict__ h0lo, u16* __restrict__ h1hi,
    u16* __restrict__ h1lo, unsigned* __restrict__ flags, float* __restrict__ out) {
  __shared__ unsigned tileHi[4096], tileLo[4096];  // 16 KB + 16 KB

  const int wg = blockIdx.x;
  const int gb = wg & 15;
  const int cg = wg >> 4;
  const int tid = threadIdx.x;
  const int wave = tid >> 6;
  const int lane = tid & 63;
  const int quad = lane >> 4;
  const int l16 = lane & 15;
  const int colg = (cg << 6) + (wave << 4) + l16;

  // B fragments, AGPR-resident (round-hi split, proven numerics)
  bf16x8 Bfh[16], Bfl[16];
#pragma unroll
  for (int ki = 0; ki < 16; ++ki) {
#pragma unroll
    for (int j = 0; j < 8; ++j) {
      int k = (ki << 5) + (quad << 3) + j;
      float v = Borth[k * HDIM + colg];
      u16 hb = f2bf(v);
      u16 lb = f2bf(v - bf2f(hb));
      Bfh[ki][j] = __builtin_bit_cast(__bf16, hb);
      Bfl[ki][j] = __builtin_bit_cast(__bf16, lb);
    }
  }
  const float win = W_in[colg];
  const float bm = b_mod[colg];

  u16* const g0h = h0hi + (gb << 13);  // 8192 u16 per group-plane
  u16* const g0l = h0lo + (gb << 13);
  u16* const g1h = h1hi + (gb << 13);
  u16* const g1l = h1lo + (gb << 13);
  // per-wave flag: group gb, wave id (cg*4 + wave) in 0..31; 128 B apart
  unsigned* const myflag = flags + ((gb << 5) + (cg << 2) + wave) * 32;
  unsigned* const gflags = flags + (gb << 5) * 32;
  const unsigned swz = (unsigned)((l16 & 7) << 2);

  for (int t = 0; t < TSTEPS; ++t) {
    const u64* __restrict__ cH = (const u64*)((t & 1) ? g1h : g0h);
    const u64* __restrict__ cL = (const u64*)((t & 1) ? g1l : g0l);
    u16* __restrict__ nH = (t & 1) ? g0h : g1h;
    u16* __restrict__ nL = (t & 1) ? g0l : g1l;

    // xp prefetch first: independent of the exchange, hides under staging
    const f32x4 xps = *(const f32x4*)(xp + t * BATCH + (gb << 4) + (quad << 2));

    // ---- cooperative stage: 2048 u64 per plane; 16 loads in flight ----
    u64 qh[8], ql[8];
#pragma unroll
    for (int i = 0; i < 8; ++i) {
      qh[i] = __hip_atomic_load(cH + tid + (i << 8), __ATOMIC_RELAXED,
                                __HIP_MEMORY_SCOPE_AGENT);
      ql[i] = __hip_atomic_load(cL + tid + (i << 8), __ATOMIC_RELAXED,
                                __HIP_MEMORY_SCOPE_AGENT);
    }
#pragma unroll
    for (int i = 0; i < 8; ++i) {
      int f = tid + (i << 8);        // u64 index in 2048-u64 plane
      int r = f >> 7;                // row 0..15
      unsigned du = (unsigned)(f & 127) << 1;  // dword col (even)
      unsigned phys = ((unsigned)r << 8) | (du ^ ((r & 7) << 2));
      *(u64*)(tileHi + phys) = qh[i];
      *(u64*)(tileLo + phys) = ql[i];
    }
    __syncthreads();  // the ONE barrier: stage-writes -> ds_reads

    // ---- fragment reads (swizzled) + split-bf16 MFMA [R10-proven] ----
    f32x4 a_hh = {0.f, 0.f, 0.f, 0.f};
    f32x4 a_lh = {0.f, 0.f, 0.f, 0.f};
    f32x4 a_hl = {0.f, 0.f, 0.f, 0.f};
#pragma unroll
    for (int ki = 0; ki < 16; ++ki) {
      unsigned dcol0 = (unsigned)((ki << 4) + (quad << 2));
      unsigned off = ((unsigned)l16 << 8) + (dcol0 ^ swz);
      bf16x8 ah = __builtin_bit_cast(bf16x8, *(const uint4v*)(tileHi + off));
      bf16x8 al = __builtin_bit_cast(bf16x8, *(const uint4v*)(tileLo + off));
      a_hh = __builtin_amdgcn_mfma_f32_16x16x32_bf16(ah, Bfh[ki], a_hh, 0, 0, 0);
      a_lh = __builtin_amdgcn_mfma_f32_16x16x32_bf16(al, Bfh[ki], a_lh, 0, 0, 0);
      a_hl = __builtin_amdgcn_mfma_f32_16x16x32_bf16(ah, Bfl[ki], a_hl, 0, 0, 0);
    }

    // C/D layout: row = quad*4 + r, col = l16  [R3-proven]
#pragma unroll
    for (int r = 0; r < 4; ++r) {
      float pre = a_hh[r] + a_lh[r] + a_hl[r] + xps[r] * win;
      float mm = fmaxf(fabsf(pre) + bm, 0.f);
      float hv = (pre > 0.f) ? mm : ((pre < 0.f) ? -mm : 0.f);
      int idx = (((quad << 2) + r) << 9) + colg;
      u16 hbv = f2bf(hv);
      u16 lbv = f2bf(hv - bf2f(hbv));
      __hip_atomic_store(nH + idx, hbv, __ATOMIC_RELAXED, __HIP_MEMORY_SCOPE_AGENT);
      __hip_atomic_store(nL + idx, lbv, __ATOMIC_RELAXED, __HIP_MEMORY_SCOPE_AGENT);
    }

    // ---- per-wave flag: drain own stores (vmcnt per-wave), flag, poll ----
    asm volatile("s_waitcnt vmcnt(0)" ::: "memory");
    if (lane == 0)
      __hip_atomic_store(myflag, (unsigned)(t + 1), __ATOMIC_RELAXED,
                         __HIP_MEMORY_SCOPE_AGENT);
    const unsigned target = (unsigned)(t + 1);
    int spin = 0;
    for (;;) {
      unsigned fl = __hip_atomic_load(gflags + (lane & 31) * 32, __ATOMIC_RELAXED,
                                      __HIP_MEMORY_SCOPE_AGENT);
      if (__ballot(fl >= target) == ~0ull) break;
      __builtin_amdgcn_s_sleep(1);
      if (++spin > (1 << 22)) break;  // anti-hang valve
    }
    // poll-success implies ALL waves (incl. this WG's) finished ds_reads of
    // tile(t) -> safe to overwrite tile next iteration without a 2nd barrier.
  }

  // ---- head: final h in buffer 0 (t=783 odd -> writes g0) ----
  if (cg == 0) {
    int row = tid >> 4;
    int cls = tid & 15;
    if (cls < NCLS) {
      const u16* hh = g0h + (row << 9);
      const u16* hl = g0l + (row << 9);
      float s = b_lin[cls];
      const float* wl = W_lin + cls * HDIM;
      for (int k = 0; k < HDIM; ++k) {
        unsigned hu = __hip_atomic_load(hh + k, __ATOMIC_RELAXED, __HIP_MEMORY_SCOPE_AGENT);
        unsigned lu = __hip_atomic_load(hl + k, __ATOMIC_RELAXED, __HIP_MEMORY_SCOPE_AGENT);
        s = fmaf(bf2f(hu) + bf2f(lu), wl[k], s);
      }
      out[((gb << 4) + row) * NCLS + cls] = s;
    }
  }
}

extern "C" void kernel_launch(void* const* d_in, const int* in_sizes, int n_in,
                              void* d_out, int out_size, void* d_ws, size_t ws_size,
                              hipStream_t stream) {
  const float* inputs = (const float*)d_in[0];  // 256x784
  const int* perm = (const int*)d_in[1];        // 784 (int64 -> int32 by harness)
  const float* W_skew = (const float*)d_in[2];  // 512x512
  const float* W_in = (const float*)d_in[3];    // 512
  const float* b_mod = (const float*)d_in[4];   // 512
  const float* W_lin = (const float*)d_in[5];   // 10x512
  const float* b_lin = (const float*)d_in[6];   // 10
  float* out = (float*)d_out;

  char* ws = (char*)d_ws;
  unsigned* flags = (unsigned*)ws;            // 16 grp x 32 waves x 128 B = 64 KB
  u16* h0hi = (u16*)(ws + 65536);             // 4 planes x 256 KB = 1 MB
  u16* h0lo = h0hi + BATCH * HDIM;
  u16* h1hi = h0lo + BATCH * HDIM;
  u16* h1lo = h1hi + BATCH * HDIM;
  float* xp = (float*)(h1lo + BATCH * HDIM);  // 0.77 MB
  float* X = xp + TSTEPS * BATCH;             // 1 MB
  float* P = X + HDIM * HDIM;                 // 1 MB
  float* Q = P + HDIM * HDIM;                 // 1 MB  (total ~4.9 MB)

  hipMemsetAsync(flags, 0, 65536, stream);
  hipMemsetAsync(h0hi, 0, (size_t)BATCH * HDIM * 2 * sizeof(u16), stream);  // h0 hi+lo

  gather_xp<<<TSTEPS, 256, 0, stream>>>(inputs, perm, xp);
  build_X<<<(HDIM * HDIM) / 256, 256, 0, stream>>>(W_skew, X);

  // expm(A) = (T6(A/32))^(2^5), Horner -- fp32 gemm512 [proven numerics]
  axpyI<<<(HDIM * HDIM) / 256, 256, 0, stream>>>(P, X, 1.f / 6.f);
  float* a = P;
  float* b = Q;
  for (int k = 5; k >= 1; --k) {
    gemm512<<<dim3(8, 8), dim3(16, 16), 0, stream>>>(b, X, a, 1.f / (float)k, 1);
    float* tmp = a; a = b; b = tmp;
  }
  for (int i = 0; i < 5; ++i) {
    gemm512<<<dim3(8, 8), dim3(16, 16), 0, stream>>>(b, a, a, 1.f, 0);
    float* tmp = a; a = b; b = tmp;
  }
  // a == P (10 swaps -> back to P)

  rnn_main<<<NGRP * WGPG, 256, 0, stream>>>(xp, a, W_in, b_mod, W_lin, b_lin,
                                            h0hi, h0lo, h1hi, h1lo, flags, out);
  (void)in_sizes; (void)n_in; (void)out_size; (void)ws_size;
}